// Round 8
// baseline (64.360 us; speedup 1.0000x reference)
//
#include <hip/hip_runtime.h>

#define SEQ 1024

typedef __attribute__((ext_vector_type(2))) float f2;

// h storage: row k = two 16B slots s=2k, 2k+1; physical slot P(s)=s^((s>>6)&7)
// (word addr 4*P). Bijective involution (bits 0..2 XORed by untouched bits 6..8).
// Bank clusters (4-bank groups) = P&7:
//  - inner key read: slot sbase^2i -> cluster (m&7)^(2i&7): 16 m-lanes hit all
//    8 clusters 2x -> 2-way, free (m136). Do NOT linearize the address
//    sequence -- that collapses clusters to 2 (8-way). 2 v_xor/iter is the price.
//  - stage-0 store: 64 consecutive rows/wave -> all clusters busy, BW-optimal.
//  - q-loads: 16-lane broadcast groups, 4 distinct slots/read.
static __device__ __forceinline__ int slot_addr(int s) {
    return (s ^ ((s >> 6) & 7)) << 2;
}

// ---- VOP3P packed-f32 helpers with operand-select broadcasts ----
// Semantics: result.lo uses op_sel[i] half of src i; result.hi uses
// op_sel_hi[i]. Broadcasting via op_sel is FREE (no v_mov register builds).
// d = a * {b.lo, b.lo}
static __device__ __forceinline__ f2 pk_mul_bl(f2 a, f2 b) {
    f2 d;
    asm("v_pk_mul_f32 %0, %1, %2 op_sel:[0,0] op_sel_hi:[1,0]"
        : "=&v"(d) : "v"(a), "v"(b));
    return d;
}
// d = a * {b.lo,b.lo} + c
static __device__ __forceinline__ f2 pk_fma_bl(f2 a, f2 b, f2 c) {
    f2 d;
    asm("v_pk_fma_f32 %0, %1, %2, %3 op_sel:[0,0,0] op_sel_hi:[1,0,1]"
        : "=&v"(d) : "v"(a), "v"(b), "v"(c));
    return d;
}
// d = a * {b.hi,b.hi} + c
static __device__ __forceinline__ f2 pk_fma_bh(f2 a, f2 b, f2 c) {
    f2 d;
    asm("v_pk_fma_f32 %0, %1, %2, %3 op_sel:[0,1,0] op_sel_hi:[1,1,1]"
        : "=&v"(d) : "v"(a), "v"(b), "v"(c));
    return d;
}
// d = {a.lo,a.lo} * b + c
static __device__ __forceinline__ f2 pk_fma_al(f2 a, f2 b, f2 c) {
    f2 d;
    asm("v_pk_fma_f32 %0, %1, %2, %3 op_sel:[0,0,0] op_sel_hi:[0,1,1]"
        : "=&v"(d) : "v"(a), "v"(b), "v"(c));
    return d;
}
// d = {a.hi,a.hi} * b + c
static __device__ __forceinline__ f2 pk_fma_ah(f2 a, f2 b, f2 c) {
    f2 d;
    asm("v_pk_fma_f32 %0, %1, %2, %3 op_sel:[1,0,0] op_sel_hi:[1,1,1]"
        : "=&v"(d) : "v"(a), "v"(b), "v"(c));
    return d;
}

// DPP quad-perm butterfly add: v += v[lane ^ 1] (0xB1) / v[lane ^ 2] (0x4E).
// VALU full-rate -- replaces __shfl_xor's ds_bpermute (LDS pipe).
template <int CTRL>
static __device__ __forceinline__ float dpp_xor_add(float v) {
    const int r = __builtin_amdgcn_mov_dpp(__float_as_int(v), CTRL, 0xF, 0xF, true);
    return v + __int_as_float(r);
}

// Closed-form qlayer for one token row y[0..7]:
// angles a = {y0+t0, y1+t1, y2+y3+t2, t3, y4+t4, y5+t5, y6+t6, y7+t7}
// c_w = cos(a_w); out[0] = c1..c7, out[w] = c0..cw (w>=1).
static __device__ __forceinline__ void qrow(const float th[8], const float y[8], float o[8]) {
    float a[8];
    a[0] = y[0] + th[0];
    a[1] = y[1] + th[1];
    a[2] = y[2] + y[3] + th[2];
    a[3] = th[3];
    a[4] = y[4] + th[4];
    a[5] = y[5] + th[5];
    a[6] = y[6] + th[6];
    a[7] = y[7] + th[7];
    float c[8];
#pragma unroll
    for (int w = 0; w < 8; ++w) c[w] = __cosf(a[w]);
    o[1] = c[0] * c[1];
#pragma unroll
    for (int w = 2; w < 8; ++w) o[w] = o[w - 1] * c[w];
    float s = c[7];
#pragma unroll
    for (int w = 6; w >= 1; --w) s *= c[w];
    o[0] = s;
}

// Fused qlayer -> 2-head attention (dk=4) -> qlayer.
// v9 = v8 (best measured: DPP reduction, merged collector) with the inner
// loop's f2 math forced to VOP3P v_pk_fma_f32 via inline asm + op_sel
// broadcasts. Tests (and captures) the "compiler scalarizes <2 x float>"
// theory: guaranteed 32 pk-ops + 8 exp per key-iter vs possibly ~70 scalar.
// Grid 512 blocks x 256 threads, launch_bounds(256,4) (VGPR cap 128; R5
// showed (512,4) caps at 64 -> catastrophic spill).
__global__ __launch_bounds__(256, 4) void mhaq_fused(const float* __restrict__ x,
                                                     const float* __restrict__ theta,
                                                     float* __restrict__ out) {
    __shared__ __align__(16) float smem[8192 + 2816];
    float* const part = smem + 8192;

    const int b   = blockIdx.x >> 5;         // batch
    const int qof = (blockIdx.x & 31) << 5;  // first query of this block's 32
    const int t   = threadIdx.x;

    float th[8];
#pragma unroll
    for (int w = 0; w < 8; ++w) th[w] = theta[w];

    // ---- Stage 0: h[b] (1024 x 8) into LDS (4 rows/thread) ----
    const float4* xb = (const float4*)(x + (size_t)b * SEQ * 8);
    float4 v0[4], v1[4];
#pragma unroll
    for (int r = 0; r < 4; ++r) {
        const int k = t + (r << 8);
        v0[r] = xb[2 * k];
        v1[r] = xb[2 * k + 1];
    }
#pragma unroll
    for (int r = 0; r < 4; ++r) {
        const int k = t + (r << 8);
        const float y[8] = {v0[r].x, v0[r].y, v0[r].z, v0[r].w,
                            v1[r].x, v1[r].y, v1[r].z, v1[r].w};
        float o[8];
        qrow(th, y, o);
        *(float4*)&smem[slot_addr(2 * k)]     = make_float4(o[0], o[1], o[2], o[3]);
        *(float4*)&smem[slot_addr(2 * k + 1)] = make_float4(o[4], o[5], o[6], o[7]);
    }
    __syncthreads();

    // ---- Stage 2: attention inner loop ----
    const int lane = t & 63;
    const int wv   = t >> 6;      // wave 0..3
    const int qs   = wv >> 1;     // 16-query set 0/1
    const int kh   = wv & 1;      // key half 0/1 (512 keys)
    const int g    = lane >> 4;   // 4-query group 0..3
    const int m    = lane & 15;   // 32-key chunk 0..15
    const int q0   = qof + (qs << 4) + (g << 2);

    const float qscale = 0.5f * 1.44269504f;  // 1/sqrt(dk) * log2(e)
    float4 qa[4], qb[4];
#pragma unroll
    for (int qq = 0; qq < 4; ++qq) {
        qa[qq] = *(const float4*)&smem[slot_addr(2 * (q0 + qq))];      // broadcast
        qb[qq] = *(const float4*)&smem[slot_addr(2 * (q0 + qq) + 1)];  // broadcast
    }
    // query-packed fragments: pk0[p][d] = {q(2p)_d, q(2p+1)_d}*s (head0 dims),
    // pk1[p][d] = same for dims 4..7 (head1).
    f2 pk0[2][4], pk1[2][4];
#pragma unroll
    for (int p = 0; p < 2; ++p) {
        pk0[p][0] = f2{qa[2 * p].x, qa[2 * p + 1].x} * qscale;
        pk0[p][1] = f2{qa[2 * p].y, qa[2 * p + 1].y} * qscale;
        pk0[p][2] = f2{qa[2 * p].z, qa[2 * p + 1].z} * qscale;
        pk0[p][3] = f2{qa[2 * p].w, qa[2 * p + 1].w} * qscale;
        pk1[p][0] = f2{qb[2 * p].x, qb[2 * p + 1].x} * qscale;
        pk1[p][1] = f2{qb[2 * p].y, qb[2 * p + 1].y} * qscale;
        pk1[p][2] = f2{qb[2 * p].z, qb[2 * p + 1].z} * qscale;
        pk1[p][3] = f2{qb[2 * p].w, qb[2 * p + 1].w} * qscale;
    }

    // accumulators: lp0/lp1[p] = packed {l_{2p}, l_{2p+1}} per head;
    // a01..a67[qq] = attention numerators (head0: 01/23, head1: 45/67).
    f2 lp0[2], lp1[2];
    f2 a01[4], a23[4], a45[4], a67[4];
#pragma unroll
    for (int p = 0; p < 2; ++p) { lp0[p] = f2{0.f, 0.f}; lp1[p] = f2{0.f, 0.f}; }
#pragma unroll
    for (int qq = 0; qq < 4; ++qq) {
        a01[qq] = f2{0.f, 0.f};
        a23[qq] = f2{0.f, 0.f};
        a45[qq] = f2{0.f, 0.f};
        a67[qq] = f2{0.f, 0.f};
    }

    const int sbase = (kh << 10) + (m << 6);  // slot of this lane's first key
    const int abase = slot_addr(sbase);       // word addr; low 6 bits of sbase = 0
#pragma unroll
    for (int i = 0; i < 32; ++i) {
        // slot sbase+2i -> word abase ^ (8i); +1 slot -> ^4 (no carries, 2i+1<64)
        const float4 k0 = *(const float4*)&smem[abase ^ (i << 3)];
        const float4 k1 = *(const float4*)&smem[abase ^ ((i << 3) | 4)];
        const f2 k01 = {k0.x, k0.y}, k23 = {k0.z, k0.w};
        const f2 k45 = {k1.x, k1.y}, k67 = {k1.z, k1.w};
#pragma unroll
        for (int p = 0; p < 2; ++p) {
            // packed dots: d0 = {score_{q2p}, score_{q2p+1}} head0, d1 head1
            f2 d0 = pk_mul_bl(pk0[p][0], k01);        // * k_0
            d0 = pk_fma_bh(pk0[p][1], k01, d0);       // + q_1 * k_1
            d0 = pk_fma_bl(pk0[p][2], k23, d0);       // + q_2 * k_2
            d0 = pk_fma_bh(pk0[p][3], k23, d0);       // + q_3 * k_3
            f2 d1 = pk_mul_bl(pk1[p][0], k45);
            d1 = pk_fma_bh(pk1[p][1], k45, d1);
            d1 = pk_fma_bl(pk1[p][2], k67, d1);
            d1 = pk_fma_bh(pk1[p][3], k67, d1);
            f2 e0, e1;
            e0.x = __builtin_amdgcn_exp2f(d0.x);
            e0.y = __builtin_amdgcn_exp2f(d0.y);
            e1.x = __builtin_amdgcn_exp2f(d1.x);
            e1.y = __builtin_amdgcn_exp2f(d1.y);
            lp0[p] += e0;
            lp1[p] += e1;
            a01[2 * p]     = pk_fma_al(e0, k01, a01[2 * p]);      // e_{q2p} * {k0,k1}
            a23[2 * p]     = pk_fma_al(e0, k23, a23[2 * p]);
            a01[2 * p + 1] = pk_fma_ah(e0, k01, a01[2 * p + 1]);  // e_{q2p+1}
            a23[2 * p + 1] = pk_fma_ah(e0, k23, a23[2 * p + 1]);
            a45[2 * p]     = pk_fma_al(e1, k45, a45[2 * p]);
            a67[2 * p]     = pk_fma_al(e1, k67, a67[2 * p]);
            a45[2 * p + 1] = pk_fma_ah(e1, k45, a45[2 * p + 1]);
            a67[2 * p + 1] = pk_fma_ah(e1, k67, a67[2 * p + 1]);
        }
    }

    // ---- 2-step DPP quad-perm reduction over m bits 0..1 (VALU, not LDS) ----
    float buf[40];
#pragma unroll
    for (int qq = 0; qq < 4; ++qq) {
        const int p = qq >> 1, hi = qq & 1;
        buf[qq * 10 + 0] = hi ? lp0[p].y : lp0[p].x;
        buf[qq * 10 + 1] = hi ? lp1[p].y : lp1[p].x;
        buf[qq * 10 + 2] = a01[qq].x;
        buf[qq * 10 + 3] = a01[qq].y;
        buf[qq * 10 + 4] = a23[qq].x;
        buf[qq * 10 + 5] = a23[qq].y;
        buf[qq * 10 + 6] = a45[qq].x;
        buf[qq * 10 + 7] = a45[qq].y;
        buf[qq * 10 + 8] = a67[qq].x;
        buf[qq * 10 + 9] = a67[qq].y;
    }
#pragma unroll
    for (int j = 0; j < 40; ++j)
        buf[j] = dpp_xor_add<0x4E>(dpp_xor_add<0xB1>(buf[j]));

    // ---- dump: survivors m%4==0 -> 16 rows/wave, 64 rows x 44 words ----
    // float4 #ii at word 44*rid+4*ii -> cluster (3*rid+ii)&7; consecutive rid
    // cycle all clusters -> 2-way, free. (part separate from h: no pre-barrier.)
    if ((m & 3) == 0) {
        const int rid = (wv << 4) + (g << 2) + (m >> 2);
        float4* pp = (float4*)&part[rid * 44];
#pragma unroll
        for (int ii = 0; ii < 10; ++ii) pp[ii] = ((const float4*)buf)[ii];
    }
    __syncthreads();

    // ---- epilogue (merged collector): thread q < 32 sums its 8 partial
    // rows directly and finalizes query qof+q. ----
    if (t < 32) {
        const int qs2 = t >> 4, g2 = (t >> 2) & 3, qq = t & 3;
        float r[10];
#pragma unroll
        for (int j = 0; j < 10; ++j) r[j] = 0.f;
#pragma unroll
        for (int kh2 = 0; kh2 < 2; ++kh2)
#pragma unroll
            for (int mm = 0; mm < 4; ++mm) {
                const int base = ((((qs2 << 1) + kh2) << 4) + (g2 << 2) + mm) * 44 + qq * 10;
#pragma unroll
                for (int j = 0; j < 10; ++j) r[j] += part[base + j];
            }
        const float inv0 = 1.0f / r[0];
        const float inv1 = 1.0f / r[1];
        const float y[8] = {r[2] * inv0, r[3] * inv0, r[4] * inv0, r[5] * inv0,
                            r[6] * inv1, r[7] * inv1, r[8] * inv1, r[9] * inv1};
        float o[8];
        qrow(th, y, o);
        float4* op = (float4*)(out + ((size_t)(b * SEQ + qof + t)) * 8);
        op[0] = make_float4(o[0], o[1], o[2], o[3]);
        op[1] = make_float4(o[4], o[5], o[6], o[7]);
    }
}

extern "C" void kernel_launch(void* const* d_in, const int* in_sizes, int n_in,
                              void* d_out, int out_size, void* d_ws, size_t ws_size,
                              hipStream_t stream) {
    const float* x     = (const float*)d_in[0];
    const float* theta = (const float*)d_in[1];
    float* out         = (float*)d_out;
    mhaq_fused<<<dim3(512), dim3(256), 0, stream>>>(x, theta, out);
}